// Round 3
// baseline (141.371 us; speedup 1.0000x reference)
//
#include <hip/hip_runtime.h>
#include <hip/hip_bf16.h>
#include <stdint.h>

// Problem dims (fixed by reference setup_inputs)
#define BQ   8192   // query rows
#define DIM  1024   // feature dim
#define NK   2048   // number of keys/values

typedef unsigned short u16;
using f32x4  = __attribute__((ext_vector_type(4))) float;
using bf16x8 = __attribute__((ext_vector_type(8))) __bf16;
using u16x4  = __attribute__((ext_vector_type(4))) unsigned short;

// ---------- helpers ----------

__device__ __forceinline__ u16 f2bf(float f) {
    uint32_t u = __float_as_uint(f);
    u += 0x7FFFu + ((u >> 16) & 1u);
    return (u16)(u >> 16);
}

__device__ __forceinline__ void gload_lds16(const void* g, void* l) {
    __builtin_amdgcn_global_load_lds(
        (const __attribute__((address_space(1))) void*)g,
        (__attribute__((address_space(3))) void*)l,
        16, 0, 0);
}

__device__ __forceinline__ f32x4 mfma16(bf16x8 a, bf16x8 b, f32x4 c) {
    return __builtin_amdgcn_mfma_f32_16x16x32_bf16(a, b, c, 0, 0, 0);
}

template<int N>
__device__ __forceinline__ void vmcnt_wait() {
    if constexpr (N == 0)      asm volatile("s_waitcnt vmcnt(0)" ::: "memory");
    else if constexpr (N == 2) asm volatile("s_waitcnt vmcnt(2)" ::: "memory");
    else if constexpr (N == 3) asm volatile("s_waitcnt vmcnt(3)" ::: "memory");
    else if constexpr (N == 4) asm volatile("s_waitcnt vmcnt(4)" ::: "memory");
    else if constexpr (N == 5) asm volatile("s_waitcnt vmcnt(5)" ::: "memory");
    else if constexpr (N == 6) asm volatile("s_waitcnt vmcnt(6)" ::: "memory");
}

__device__ __forceinline__ void lgkm0_fence() {
    asm volatile("s_waitcnt lgkmcnt(0)" ::: "memory");
    __builtin_amdgcn_sched_barrier(0);
}

// ---------- stage 0: fp32 -> bf16 convert ----------

__global__ void cvt_f32_bf16(const float* __restrict__ in, u16* __restrict__ out, int n4) {
    int i = blockIdx.x * blockDim.x + threadIdx.x;
    if (i < n4) {
        f32x4 v = reinterpret_cast<const f32x4*>(in)[i];
        u16x4 o;
        o.x = f2bf(v[0]); o.y = f2bf(v[1]); o.z = f2bf(v[2]); o.w = f2bf(v[3]);
        reinterpret_cast<u16x4*>(out)[i] = o;
    }
}

// transpose V (NK x DIM fp32) -> VT (DIM x NK bf16)
__global__ void transpose_cvt(const float* __restrict__ V, u16* __restrict__ VT) {
    __shared__ float tile[32][33];
    int d0 = blockIdx.x * 32;
    int n0 = blockIdx.y * 32;
    int tx = threadIdx.x, ty = threadIdx.y;
#pragma unroll
    for (int i = 0; i < 4; ++i)
        tile[ty + i * 8][tx] = V[(size_t)(n0 + ty + i * 8) * DIM + d0 + tx];
    __syncthreads();
#pragma unroll
    for (int i = 0; i < 4; ++i)
        VT[(size_t)(d0 + ty + i * 8) * NK + n0 + tx] = f2bf(tile[tx][ty + i * 8]);
}

// ---------- 8-phase deep-pipelined GEMM: C = scale * A[M,K] * B[N,K]^T ----------
// BM=256, BN in {256,128}. 8 waves (2M x 4N), BK=64, half-tile staging (1 per phase,
// 3-5 half-tiles in flight), counted vmcnt (never 0 in steady state), 2 barriers per
// phase, setprio around 16-MFMA clusters, T2 XOR-swizzled LDS, XCD block swizzle.
// Grid must be 256 blocks (nbn == 8).

template<int BN>
__global__ __launch_bounds__(512, 2)
void gemm8p(const u16* __restrict__ A, const u16* __restrict__ B, float* __restrict__ C,
            int K, int lda, int ldb, int ldc, float scale) {
    constexpr int HB   = BN / 2;          // rows per B half-tile (128 or 64)
    constexpr int NREP = BN / 64;         // n-frags per wave (4 or 2)
    constexpr int NH   = NREP / 2;        // n-frags per half (2 or 1)
    constexpr int AC   = 2;               // gload calls per A half-tile (per wave)
    constexpr int BC   = (BN == 256) ? 2 : 1;
    // counted-vmcnt constants (derived from issue/consume stream)
    constexpr int N1  = 2 * AC + BC;      // end-P1 steady: 6 / 5
    constexpr int N1T = AC;               // end-P1 tail:   2
    constexpr int N2  = AC + 2 * BC;      // end-P2 steady: 6 / 4
    constexpr int N4  = 2 * AC + BC;      // end-P4 steady: 6 / 5
    constexpr int N4T = AC + BC;          // end-P4 tail:   4 / 3

    __shared__ u16 Al[2][2][128 * 64];    // [dbuf][half][row*64]
    __shared__ u16 Bl[2][2][HB * 64];

    const int tid  = threadIdx.x;
    const int wave = tid >> 6;
    const int lane = tid & 63;
    const int wr = wave >> 2;             // 0..1 (M)
    const int wc = wave & 3;              // 0..3 (N)

    // XCD-aware bijective swizzle; nbn == 8 hardcoded
    int id = blockIdx.x;
    const int cpx = gridDim.x >> 3;
    id = (id & 7) * cpx + (id >> 3);
    const int bm = id >> 3;
    const int bn = id & 7;

    // ---- staging geometry: one call = 64 rows x 128B, wave w covers rows w*8..w*8+7
    const int lsub = lane >> 3;
    const int lslot = lane & 7;
    const int srcCol = ((lslot ^ lsub) << 3);   // inverse-swizzled k offset (elements)

    const u16* aG = A + (size_t)(bm * 256 + wave * 8 + lsub) * lda + srcCol;
    const u16* bG = B + (size_t)(bn * BN  + wave * 8 + lsub) * ldb + srcCol;
    const int ldsChunk = (wave * 8) * 64;       // u16 offset of this wave's 1KB slice

    auto STAGE_A = [&](int buf, int h, int kt) {
#pragma unroll
        for (int c = 0; c < AC; ++c)
            gload_lds16(aG + (size_t)(h * 128 + c * 64) * lda + (size_t)kt * 64,
                        &Al[buf][h][c * 64 * 64 + ldsChunk]);
    };
    auto STAGE_B = [&](int buf, int h, int kt) {
#pragma unroll
        for (int c = 0; c < BC; ++c)
            gload_lds16(bG + (size_t)(h * HB + c * 64) * ldb + (size_t)kt * 64,
                        &Bl[buf][h][c * 64 * 64 + ldsChunk]);
    };

    // ---- swizzled fragment reads (row stride 128B; byte ^= (row&7)<<4)
    const int fr = lane & 15;
    const int cXor = (((lane >> 4) << 4) ^ ((lane & 7) << 4));
    auto LDA = [&](int buf, int h, int mi, int kk) -> bf16x8 {   // mi 0..3 within half
        int off = (wr * 64 + mi * 16 + fr) * 128 + (cXor ^ (kk << 6));
        return *reinterpret_cast<const bf16x8*>(
            reinterpret_cast<const char*>(&Al[buf][h][0]) + off);
    };
    auto LDB = [&](int buf, int h, int ni, int kk) -> bf16x8 {   // ni 0..NH-1 within half
        int r = (BN == 256 ? wc * 32 + ni * 16 : wc * 16) + fr;
        int off = r * 128 + (cXor ^ (kk << 6));
        return *reinterpret_cast<const bf16x8*>(
            reinterpret_cast<const char*>(&Bl[buf][h][0]) + off);
    };

    f32x4 acc[8][NREP] = {};
    const int NT = K >> 6;                // >= 2 always here

    // ---- prologue: stage tile0 (4 half-tiles) + HA0(1); wait for HA0(0)+HB0(0)
    STAGE_A(0, 0, 0);
    STAGE_B(0, 0, 0);
    STAGE_B(0, 1, 0);
    STAGE_A(0, 1, 0);
    STAGE_A(1, 0, 1);
    vmcnt_wait<N4>();
    __builtin_amdgcn_s_barrier();

    for (int t = 0; t < NT; ++t) {
        const int cb = t & 1, nb = cb ^ 1;
        bf16x8 af[4][2], bflo[NH][2], bfhi[NH][2];

        // ===== P1: Q00 (m0-3 x n-lo), reads A-h0 + B-h0; stage HB0(t+1) =====
#pragma unroll
        for (int mi = 0; mi < 4; ++mi) { af[mi][0] = LDA(cb, 0, mi, 0); af[mi][1] = LDA(cb, 0, mi, 1); }
#pragma unroll
        for (int ni = 0; ni < NH; ++ni) { bflo[ni][0] = LDB(cb, 0, ni, 0); bflo[ni][1] = LDB(cb, 0, ni, 1); }
        if (t + 1 < NT) { STAGE_B(nb, 0, t + 1); vmcnt_wait<N1>(); }
        else            { vmcnt_wait<N1T>(); }
        __builtin_amdgcn_s_barrier();
        lgkm0_fence();
        __builtin_amdgcn_s_setprio(1);
#pragma unroll
        for (int mi = 0; mi < 4; ++mi)
#pragma unroll
            for (int ni = 0; ni < NH; ++ni) {
                acc[mi][ni] = mfma16(af[mi][0], bflo[ni][0], acc[mi][ni]);
                acc[mi][ni] = mfma16(af[mi][1], bflo[ni][1], acc[mi][ni]);
            }
        __builtin_amdgcn_s_setprio(0);
        __builtin_amdgcn_s_barrier();

        // ===== P2: Q01 (m0-3 x n-hi), reads B-h1; stage HB1(t+1) =====
#pragma unroll
        for (int ni = 0; ni < NH; ++ni) { bfhi[ni][0] = LDB(cb, 1, ni, 0); bfhi[ni][1] = LDB(cb, 1, ni, 1); }
        if (t + 1 < NT) { STAGE_B(nb, 1, t + 1); vmcnt_wait<N2>(); }
        else            { vmcnt_wait<0>(); }
        __builtin_amdgcn_s_barrier();
        lgkm0_fence();
        __builtin_amdgcn_s_setprio(1);
#pragma unroll
        for (int mi = 0; mi < 4; ++mi)
#pragma unroll
            for (int ni = 0; ni < NH; ++ni) {
                acc[mi][NH + ni] = mfma16(af[mi][0], bfhi[ni][0], acc[mi][NH + ni]);
                acc[mi][NH + ni] = mfma16(af[mi][1], bfhi[ni][1], acc[mi][NH + ni]);
            }
        __builtin_amdgcn_s_setprio(0);
        __builtin_amdgcn_s_barrier();

        // ===== P3: Q11 (m4-7 x n-hi), reads A-h1; stage HA1(t+1) =====
#pragma unroll
        for (int mi = 0; mi < 4; ++mi) { af[mi][0] = LDA(cb, 1, mi, 0); af[mi][1] = LDA(cb, 1, mi, 1); }
        if (t + 1 < NT) STAGE_A(nb, 1, t + 1);
        __builtin_amdgcn_s_barrier();
        lgkm0_fence();
        __builtin_amdgcn_s_setprio(1);
#pragma unroll
        for (int mi = 0; mi < 4; ++mi)
#pragma unroll
            for (int ni = 0; ni < NH; ++ni) {
                acc[4 + mi][NH + ni] = mfma16(af[mi][0], bfhi[ni][0], acc[4 + mi][NH + ni]);
                acc[4 + mi][NH + ni] = mfma16(af[mi][1], bfhi[ni][1], acc[4 + mi][NH + ni]);
            }
        __builtin_amdgcn_s_setprio(0);
        __builtin_amdgcn_s_barrier();

        // ===== P4: Q10 (m4-7 x n-lo), no reads; stage HA0(t+2) =====
        if (t + 2 < NT) STAGE_A(cb, 0, t + 2);
        if (t + 1 < NT) {
            if (t + 2 < NT) vmcnt_wait<N4>(); else vmcnt_wait<N4T>();
        }
        __builtin_amdgcn_s_barrier();
        __builtin_amdgcn_s_setprio(1);
#pragma unroll
        for (int mi = 0; mi < 4; ++mi)
#pragma unroll
            for (int ni = 0; ni < NH; ++ni) {
                acc[4 + mi][ni] = mfma16(af[mi][0], bflo[ni][0], acc[4 + mi][ni]);
                acc[4 + mi][ni] = mfma16(af[mi][1], bflo[ni][1], acc[4 + mi][ni]);
            }
        __builtin_amdgcn_s_setprio(0);
        __builtin_amdgcn_s_barrier();
    }

    // ---- epilogue: C/D layout col = lane&15, row = (lane>>4)*4 + j
    const int jrow = ((lane >> 4) << 2);
#pragma unroll
    for (int m = 0; m < 8; ++m) {
        int gr = bm * 256 + (m < 4 ? 0 : 128) + wr * 64 + (m & 3) * 16 + jrow;
#pragma unroll
        for (int j = 0; j < 4; ++j) {
            float* cp = C + (size_t)(gr + j) * ldc;
#pragma unroll
            for (int n = 0; n < NREP; ++n) {
                int gc = bn * BN + (n < NH ? 0 : HB)
                       + (BN == 256 ? wc * 32 : wc * 16) + (n % NH) * 16 + fr;
                cp[gc] = acc[m][n][j] * scale;
            }
        }
    }
}

// ---------- stage 2: row softmax1 + 16-step sigmoid long-division reciprocal ----------

__global__ void softmax_recip(const float* __restrict__ S, u16* __restrict__ W) {
    const int row  = blockIdx.x;
    const int t    = threadIdx.x;
    const int wid  = t >> 6;
    const int lane = t & 63;

    const float* s = S + (size_t)row * NK;
    f32x4 v0 = reinterpret_cast<const f32x4*>(s)[t];
    f32x4 v1 = reinterpret_cast<const f32x4*>(s)[256 + t];

    float m = fmaxf(fmaxf(fmaxf(v0[0], v0[1]), fmaxf(v0[2], v0[3])),
                    fmaxf(fmaxf(v1[0], v1[1]), fmaxf(v1[2], v1[3])));
#pragma unroll
    for (int off = 32; off; off >>= 1) m = fmaxf(m, __shfl_xor(m, off));

    __shared__ float redm[4];
    __shared__ float reds[4];
    if (lane == 0) redm[wid] = m;
    __syncthreads();
    m = fmaxf(fmaxf(redm[0], redm[1]), fmaxf(redm[2], redm[3]));

    float e[8];
    e[0] = expf(v0[0] - m); e[1] = expf(v0[1] - m);
    e[2] = expf(v0[2] - m); e[3] = expf(v0[3] - m);
    e[4] = expf(v1[0] - m); e[5] = expf(v1[1] - m);
    e[6] = expf(v1[2] - m); e[7] = expf(v1[3] - m);
    float sum = e[0] + e[1] + e[2] + e[3] + e[4] + e[5] + e[6] + e[7];
#pragma unroll
    for (int off = 32; off; off >>= 1) sum += __shfl_xor(sum, off);
    if (lane == 0) reds[wid] = sum;
    __syncthreads();
    sum = reds[0] + reds[1] + reds[2] + reds[3];

    const float d = 1.0f + sum;

    float r = 1.0f, q = 0.0f, w = 0.5f;
#pragma unroll
    for (int i = 0; i < 16; ++i) {
        float doubled = 2.0f * r;
        float st = 1.0f / (1.0f + expf(-100.0f * (doubled - d)));
        r = doubled - d * st;
        q += w * st;
        w *= 0.5f;
    }

    u16x4 o0, o1;
    o0.x = f2bf(e[0] * q); o0.y = f2bf(e[1] * q); o0.z = f2bf(e[2] * q); o0.w = f2bf(e[3] * q);
    o1.x = f2bf(e[4] * q); o1.y = f2bf(e[5] * q); o1.z = f2bf(e[6] * q); o1.w = f2bf(e[7] * q);
    u16x4* wp = reinterpret_cast<u16x4*>(W + (size_t)row * NK);
    wp[t]       = o0;
    wp[256 + t] = o1;
}

// ---------- launch ----------

extern "C" void kernel_launch(void* const* d_in, const int* in_sizes, int n_in,
                              void* d_out, int out_size, void* d_ws, size_t ws_size,
                              hipStream_t stream) {
    const float* Q = (const float*)d_in[0];
    const float* K = (const float*)d_in[1];
    const float* V = (const float*)d_in[2];
    float* out = (float*)d_out;

    char* ws = (char*)d_ws;
    u16*   Qb  = (u16*)(ws);
    u16*   Kb  = (u16*)(ws + (16u << 20));
    u16*   VbT = (u16*)(ws + (20u << 20));
    float* S   = (float*)(ws + (24u << 20));
    u16*   W   = (u16*)(ws + (88u << 20));

    {
        int n4 = BQ * DIM / 4;
        cvt_f32_bf16<<<(n4 + 255) / 256, 256, 0, stream>>>(Q, Qb, n4);
    }
    {
        int n4 = NK * DIM / 4;
        cvt_f32_bf16<<<(n4 + 255) / 256, 256, 0, stream>>>(K, Kb, n4);
    }
    transpose_cvt<<<dim3(DIM / 32, NK / 32), dim3(32, 8), 0, stream>>>(V, VbT);

    // stage 1: S = (1/32) * Qb @ Kb^T   (M=8192, N=2048, K=1024) — 32x8 = 256 blocks
    gemm8p<256><<<(BQ / 256) * (NK / 256), 512, 0, stream>>>(
        Qb, Kb, S, DIM, DIM, DIM, NK, 0.03125f);

    // stage 2: softmax1 + reciprocal scan -> W bf16
    softmax_recip<<<BQ, 256, 0, stream>>>(S, W);

    // stage 3: out = W @ VbT^T          (M=8192, N=1024, K=2048) — 32x8 = 256 blocks
    gemm8p<128><<<(BQ / 256) * (DIM / 128), 512, 0, stream>>>(
        W, VbT, out, NK, NK, NK, DIM, 1.0f);
}

// Round 4
// 133.580 us; speedup vs baseline: 1.0583x; 1.0583x over previous
//
#include <hip/hip_runtime.h>
#include <hip/hip_bf16.h>
#include <stdint.h>

// Problem dims (fixed by reference setup_inputs)
#define BQ   8192   // query rows
#define DIM  1024   // feature dim
#define NK   2048   // number of keys/values

typedef unsigned short u16;
using f32x4  = __attribute__((ext_vector_type(4))) float;
using bf16x8 = __attribute__((ext_vector_type(8))) __bf16;
using u16x4  = __attribute__((ext_vector_type(4))) unsigned short;

// ---------- helpers ----------

__device__ __forceinline__ u16 f2bf(float f) {
    uint32_t u = __float_as_uint(f);
    u += 0x7FFFu + ((u >> 16) & 1u);
    return (u16)(u >> 16);
}

__device__ __forceinline__ void gload_lds16(const void* g, void* l) {
    __builtin_amdgcn_global_load_lds(
        (const __attribute__((address_space(1))) void*)g,
        (__attribute__((address_space(3))) void*)l,
        16, 0, 0);
}

__device__ __forceinline__ f32x4 mfma16(bf16x8 a, bf16x8 b, f32x4 c) {
    return __builtin_amdgcn_mfma_f32_16x16x32_bf16(a, b, c, 0, 0, 0);
}

template<int N>
__device__ __forceinline__ void vmcnt_wait() {
    if constexpr (N == 0)      asm volatile("s_waitcnt vmcnt(0)" ::: "memory");
    else if constexpr (N == 4) asm volatile("s_waitcnt vmcnt(4)" ::: "memory");
    else if constexpr (N == 6) asm volatile("s_waitcnt vmcnt(6)" ::: "memory");
}

__device__ __forceinline__ void lgkm0_fence() {
    asm volatile("s_waitcnt lgkmcnt(0)" ::: "memory");
    __builtin_amdgcn_sched_barrier(0);
}

// ---------- stage 0: fp32 -> bf16 convert ----------

__global__ void cvt_f32_bf16(const float* __restrict__ in, u16* __restrict__ out, int n4) {
    int i = blockIdx.x * blockDim.x + threadIdx.x;
    if (i < n4) {
        f32x4 v = reinterpret_cast<const f32x4*>(in)[i];
        u16x4 o;
        o.x = f2bf(v[0]); o.y = f2bf(v[1]); o.z = f2bf(v[2]); o.w = f2bf(v[3]);
        reinterpret_cast<u16x4*>(out)[i] = o;
    }
}

// transpose V (NK x DIM fp32) -> VT (DIM x NK bf16)
__global__ void transpose_cvt(const float* __restrict__ V, u16* __restrict__ VT) {
    __shared__ float tile[32][33];
    int d0 = blockIdx.x * 32;
    int n0 = blockIdx.y * 32;
    int tx = threadIdx.x, ty = threadIdx.y;
#pragma unroll
    for (int i = 0; i < 4; ++i)
        tile[ty + i * 8][tx] = V[(size_t)(n0 + ty + i * 8) * DIM + d0 + tx];
    __syncthreads();
#pragma unroll
    for (int i = 0; i < 4; ++i)
        VT[(size_t)(d0 + ty + i * 8) * NK + n0 + tx] = f2bf(tile[tx][ty + i * 8]);
}

// ---------- 8-phase deep-pipelined GEMM: C = scale * A[M,K] * B[N,K]^T ----------
// BM=256, BN in {256,128}. 8 waves (2M x 4N), BK=64, one half-tile staged per phase
// reaching tile t+2, ONE counted vmcnt per K-tile at end-P4 (gates all of tile t+1,
// loads aged 3-7 phases; 3 half-tiles stay in flight), 2 barriers per phase,
// setprio around MFMA clusters, T2 XOR-swizzled LDS, XCD block swizzle.
// Grid must be 256 blocks (nbn == 8). Requires NT >= 3.

template<int BN>
__global__ __launch_bounds__(512, 2)
void gemm8p(const u16* __restrict__ A, const u16* __restrict__ B, float* __restrict__ C,
            int K, int lda, int ldb, int ldc, float scale) {
    constexpr int HB   = BN / 2;          // rows per B half-tile (128 or 64)
    constexpr int NREP = BN / 64;         // n-frags per wave (4 or 2)
    constexpr int NH   = NREP / 2;        // n-frags per half (2 or 1)
    constexpr int AC   = 2;               // gload instrs per A half-tile (per thread)
    constexpr int BC   = (BN == 256) ? 2 : 1;
    // steady-state count: instrs issued after S(t+1,A-hi) = AC + 2*BC (6 / 4)
    constexpr int NS   = AC + 2 * BC;

    __shared__ u16 Al[2][2][128 * 64];    // [dbuf][half][row*64]
    __shared__ u16 Bl[2][2][HB * 64];

    const int tid  = threadIdx.x;
    const int wave = tid >> 6;
    const int lane = tid & 63;
    const int wr = wave >> 2;             // 0..1 (M)
    const int wc = wave & 3;              // 0..3 (N)

    // XCD-aware bijective swizzle; nbn == 8 hardcoded
    int id = blockIdx.x;
    const int cpx = gridDim.x >> 3;
    id = (id & 7) * cpx + (id >> 3);
    const int bm = id >> 3;
    const int bn = id & 7;

    // ---- staging geometry: one call = 64 rows x 128B; wave w covers rows w*8..w*8+7
    const int lsub  = lane >> 3;
    const int lslot = lane & 7;
    const int srcCol = ((lslot ^ lsub) << 3);   // inverse-swizzled k offset (elements)

    const u16* aG = A + (size_t)(bm * 256 + wave * 8 + lsub) * lda + srcCol;
    const u16* bG = B + (size_t)(bn * BN  + wave * 8 + lsub) * ldb + srcCol;
    const int ldsChunk = (wave * 8) * 64;       // u16 offset of this wave's 1KB slice

    auto STAGE_A = [&](int buf, int h, int kt) {
#pragma unroll
        for (int c = 0; c < AC; ++c)
            gload_lds16(aG + (size_t)(h * 128 + c * 64) * lda + (size_t)kt * 64,
                        &Al[buf][h][c * 64 * 64 + ldsChunk]);
    };
    auto STAGE_B = [&](int buf, int h, int kt) {
#pragma unroll
        for (int c = 0; c < BC; ++c)
            gload_lds16(bG + (size_t)(h * HB + c * 64) * ldb + (size_t)kt * 64,
                        &Bl[buf][h][c * 64 * 64 + ldsChunk]);
    };

    // ---- swizzled fragment reads (row stride 128B; byte ^= (row&7)<<4)
    const int fr = lane & 15;
    const int cXor = (((lane >> 4) << 4) ^ ((lane & 7) << 4));
    auto LDA = [&](int buf, int h, int mi, int kk) -> bf16x8 {   // mi 0..3 within half
        int off = (wr * 64 + mi * 16 + fr) * 128 + (cXor ^ (kk << 6));
        return *reinterpret_cast<const bf16x8*>(
            reinterpret_cast<const char*>(&Al[buf][h][0]) + off);
    };
    auto LDB = [&](int buf, int h, int ni, int kk) -> bf16x8 {   // ni 0..NH-1 within half
        int r = (BN == 256 ? wc * 32 + ni * 16 : wc * 16) + fr;
        int off = r * 128 + (cXor ^ (kk << 6));
        return *reinterpret_cast<const bf16x8*>(
            reinterpret_cast<const char*>(&Bl[buf][h][0]) + off);
    };

    f32x4 acc[8][NREP] = {};
    const int NT = K >> 6;                // 16 or 32 here (NT >= 3)

    // ---- prologue: tile 0 fully + tile 1 minus A-hi; wait tile 0 ready
    STAGE_A(0, 0, 0); STAGE_B(0, 0, 0); STAGE_B(0, 1, 0); STAGE_A(0, 1, 0);
    STAGE_A(1, 0, 1); STAGE_B(1, 0, 1); STAGE_B(1, 1, 1);
    vmcnt_wait<NS>();                     // tile-0 halves (oldest 4) complete
    __builtin_amdgcn_s_barrier();

    for (int t = 0; t < NT; ++t) {
        const int cb = t & 1, nb = cb ^ 1;
        bf16x8 af[4][2], bflo[NH][2], bfhi[NH][2];

        // ===== P1: Q00 (m0-3 x n-lo) reads A-lo,B-lo; stage S(t+1, A-hi) -> nb =====
#pragma unroll
        for (int mi = 0; mi < 4; ++mi) { af[mi][0] = LDA(cb, 0, mi, 0); af[mi][1] = LDA(cb, 0, mi, 1); }
#pragma unroll
        for (int ni = 0; ni < NH; ++ni) { bflo[ni][0] = LDB(cb, 0, ni, 0); bflo[ni][1] = LDB(cb, 0, ni, 1); }
        if (t + 1 < NT) STAGE_A(nb, 1, t + 1);
        __builtin_amdgcn_s_barrier();
        lgkm0_fence();
        __builtin_amdgcn_s_setprio(1);
#pragma unroll
        for (int mi = 0; mi < 4; ++mi)
#pragma unroll
            for (int ni = 0; ni < NH; ++ni) {
                acc[mi][ni] = mfma16(af[mi][0], bflo[ni][0], acc[mi][ni]);
                acc[mi][ni] = mfma16(af[mi][1], bflo[ni][1], acc[mi][ni]);
            }
        __builtin_amdgcn_s_setprio(0);
        __builtin_amdgcn_s_barrier();

        // ===== P2: Q01 (m0-3 x n-hi) reads B-hi; stage S(t+2, A-lo) -> cb =====
#pragma unroll
        for (int ni = 0; ni < NH; ++ni) { bfhi[ni][0] = LDB(cb, 1, ni, 0); bfhi[ni][1] = LDB(cb, 1, ni, 1); }
        if (t + 2 < NT) STAGE_A(cb, 0, t + 2);
        __builtin_amdgcn_s_barrier();
        lgkm0_fence();
        __builtin_amdgcn_s_setprio(1);
#pragma unroll
        for (int mi = 0; mi < 4; ++mi)
#pragma unroll
            for (int ni = 0; ni < NH; ++ni) {
                acc[mi][NH + ni] = mfma16(af[mi][0], bfhi[ni][0], acc[mi][NH + ni]);
                acc[mi][NH + ni] = mfma16(af[mi][1], bfhi[ni][1], acc[mi][NH + ni]);
            }
        __builtin_amdgcn_s_setprio(0);
        __builtin_amdgcn_s_barrier();

        // ===== P3: Q11 (m4-7 x n-hi) reads A-hi; stage S(t+2, B-lo) -> cb =====
#pragma unroll
        for (int mi = 0; mi < 4; ++mi) { af[mi][0] = LDA(cb, 1, mi, 0); af[mi][1] = LDA(cb, 1, mi, 1); }
        if (t + 2 < NT) STAGE_B(cb, 0, t + 2);
        __builtin_amdgcn_s_barrier();
        lgkm0_fence();
        __builtin_amdgcn_s_setprio(1);
#pragma unroll
        for (int mi = 0; mi < 4; ++mi)
#pragma unroll
            for (int ni = 0; ni < NH; ++ni) {
                acc[4 + mi][NH + ni] = mfma16(af[mi][0], bfhi[ni][0], acc[4 + mi][NH + ni]);
                acc[4 + mi][NH + ni] = mfma16(af[mi][1], bfhi[ni][1], acc[4 + mi][NH + ni]);
            }
        __builtin_amdgcn_s_setprio(0);
        __builtin_amdgcn_s_barrier();

        // ===== P4: Q10 (m4-7 x n-lo) no reads; stage S(t+2, B-hi) -> cb; ONE wait =====
        if (t + 2 < NT) STAGE_B(cb, 1, t + 2);
        if (t + 2 < NT)      vmcnt_wait<NS>();   // gates ALL of tile t+1 (aged 3-7 phases)
        else if (t + 1 < NT) vmcnt_wait<0>();    // tail: drain S(t+1,A-hi)
        __builtin_amdgcn_s_barrier();
        __builtin_amdgcn_s_setprio(1);
#pragma unroll
        for (int mi = 0; mi < 4; ++mi)
#pragma unroll
            for (int ni = 0; ni < NH; ++ni) {
                acc[4 + mi][ni] = mfma16(af[mi][0], bflo[ni][0], acc[4 + mi][ni]);
                acc[4 + mi][ni] = mfma16(af[mi][1], bflo[ni][1], acc[4 + mi][ni]);
            }
        __builtin_amdgcn_s_setprio(0);
        __builtin_amdgcn_s_barrier();
    }

    // ---- epilogue: C/D layout col = lane&15, row = (lane>>4)*4 + j
    const int jrow = ((lane >> 4) << 2);
#pragma unroll
    for (int m = 0; m < 8; ++m) {
        int gr = bm * 256 + (m < 4 ? 0 : 128) + wr * 64 + (m & 3) * 16 + jrow;
#pragma unroll
        for (int j = 0; j < 4; ++j) {
            float* cp = C + (size_t)(gr + j) * ldc;
#pragma unroll
            for (int n = 0; n < NREP; ++n) {
                int gc = bn * BN + (n < NH ? 0 : HB)
                       + (BN == 256 ? wc * 32 : wc * 16) + (n % NH) * 16 + fr;
                cp[gc] = acc[m][n][j] * scale;
            }
        }
    }
}

// ---------- stage 2: row softmax1 + 16-step sigmoid long-division reciprocal ----------

__global__ void softmax_recip(const float* __restrict__ S, u16* __restrict__ W) {
    const int row  = blockIdx.x;
    const int t    = threadIdx.x;
    const int wid  = t >> 6;
    const int lane = t & 63;

    const float* s = S + (size_t)row * NK;
    f32x4 v0 = reinterpret_cast<const f32x4*>(s)[t];
    f32x4 v1 = reinterpret_cast<const f32x4*>(s)[256 + t];

    float m = fmaxf(fmaxf(fmaxf(v0[0], v0[1]), fmaxf(v0[2], v0[3])),
                    fmaxf(fmaxf(v1[0], v1[1]), fmaxf(v1[2], v1[3])));
#pragma unroll
    for (int off = 32; off; off >>= 1) m = fmaxf(m, __shfl_xor(m, off));

    __shared__ float redm[4];
    __shared__ float reds[4];
    if (lane == 0) redm[wid] = m;
    __syncthreads();
    m = fmaxf(fmaxf(redm[0], redm[1]), fmaxf(redm[2], redm[3]));

    float e[8];
    e[0] = expf(v0[0] - m); e[1] = expf(v0[1] - m);
    e[2] = expf(v0[2] - m); e[3] = expf(v0[3] - m);
    e[4] = expf(v1[0] - m); e[5] = expf(v1[1] - m);
    e[6] = expf(v1[2] - m); e[7] = expf(v1[3] - m);
    float sum = e[0] + e[1] + e[2] + e[3] + e[4] + e[5] + e[6] + e[7];
#pragma unroll
    for (int off = 32; off; off >>= 1) sum += __shfl_xor(sum, off);
    if (lane == 0) reds[wid] = sum;
    __syncthreads();
    sum = reds[0] + reds[1] + reds[2] + reds[3];

    const float d = 1.0f + sum;

    float r = 1.0f, q = 0.0f, w = 0.5f;
#pragma unroll
    for (int i = 0; i < 16; ++i) {
        float doubled = 2.0f * r;
        float st = 1.0f / (1.0f + expf(-100.0f * (doubled - d)));
        r = doubled - d * st;
        q += w * st;
        w *= 0.5f;
    }

    u16x4 o0, o1;
    o0.x = f2bf(e[0] * q); o0.y = f2bf(e[1] * q); o0.z = f2bf(e[2] * q); o0.w = f2bf(e[3] * q);
    o1.x = f2bf(e[4] * q); o1.y = f2bf(e[5] * q); o1.z = f2bf(e[6] * q); o1.w = f2bf(e[7] * q);
    u16x4* wp = reinterpret_cast<u16x4*>(W + (size_t)row * NK);
    wp[t]       = o0;
    wp[256 + t] = o1;
}

// ---------- launch ----------

extern "C" void kernel_launch(void* const* d_in, const int* in_sizes, int n_in,
                              void* d_out, int out_size, void* d_ws, size_t ws_size,
                              hipStream_t stream) {
    const float* Q = (const float*)d_in[0];
    const float* K = (const float*)d_in[1];
    const float* V = (const float*)d_in[2];
    float* out = (float*)d_out;

    char* ws = (char*)d_ws;
    u16*   Qb  = (u16*)(ws);
    u16*   Kb  = (u16*)(ws + (16u << 20));
    u16*   VbT = (u16*)(ws + (20u << 20));
    float* S   = (float*)(ws + (24u << 20));
    u16*   W   = (u16*)(ws + (88u << 20));

    {
        int n4 = BQ * DIM / 4;
        cvt_f32_bf16<<<(n4 + 255) / 256, 256, 0, stream>>>(Q, Qb, n4);
    }
    {
        int n4 = NK * DIM / 4;
        cvt_f32_bf16<<<(n4 + 255) / 256, 256, 0, stream>>>(K, Kb, n4);
    }
    transpose_cvt<<<dim3(DIM / 32, NK / 32), dim3(32, 8), 0, stream>>>(V, VbT);

    // stage 1: S = (1/32) * Qb @ Kb^T   (M=8192, N=2048, K=1024) — 32x8 = 256 blocks
    gemm8p<256><<<(BQ / 256) * (NK / 256), 512, 0, stream>>>(
        Qb, Kb, S, DIM, DIM, DIM, NK, 0.03125f);

    // stage 2: softmax1 + reciprocal scan -> W bf16
    softmax_recip<<<BQ, 256, 0, stream>>>(S, W);

    // stage 3: out = W @ VbT^T          (M=8192, N=1024, K=2048) — 32x8 = 256 blocks
    gemm8p<128><<<(BQ / 256) * (DIM / 128), 512, 0, stream>>>(
        W, VbT, out, NK, NK, NK, DIM, 1.0f);
}